// Round 1
// baseline (45.956 us; speedup 1.0000x reference)
//
#include <hip/hip_runtime.h>

// KV cache append: out[b,h] = concat(k_cache[b,h] (65536 rows), x[b,h] (16 rows))
// B=1, H=8, S=65536, D=64, NEW=16, fp32.
// Per head: cache = 65536*64 = 4,194,304 floats = 1,048,576 float4 (== 2^20)
//           x     =    16*64 =     1,024 floats =       256 float4
//           out   = 65552*64 = 4,195,328 floats = 1,048,832 float4

#define CACHE_F4_PER_HEAD (1048576LL)   // 2^20
#define OUT_F4_PER_HEAD   (1048832LL)
#define X_F4_PER_HEAD     (256)
#define N_HEADS           (8)

__global__ void kv_copy_cache(const float4* __restrict__ src, float4* __restrict__ dst) {
    const long long total = (long long)N_HEADS * CACHE_F4_PER_HEAD;  // 8,388,608
    long long i = (long long)blockIdx.x * blockDim.x + threadIdx.x;
    const long long stride = (long long)gridDim.x * blockDim.x;
    for (; i < total; i += stride) {
        long long head = i >> 20;               // / 2^20
        long long r    = i & (CACHE_F4_PER_HEAD - 1);
        dst[head * OUT_F4_PER_HEAD + r] = src[i];
    }
}

__global__ void kv_copy_x(const float4* __restrict__ x, float4* __restrict__ dst) {
    int i = blockIdx.x * blockDim.x + threadIdx.x;   // 0..2047
    if (i < N_HEADS * X_F4_PER_HEAD) {
        int head = i >> 8;
        int r    = i & (X_F4_PER_HEAD - 1);
        dst[head * OUT_F4_PER_HEAD + CACHE_F4_PER_HEAD + r] = x[i];
    }
}

extern "C" void kernel_launch(void* const* d_in, const int* in_sizes, int n_in,
                              void* d_out, int out_size, void* d_ws, size_t ws_size,
                              hipStream_t stream) {
    const float4* x     = (const float4*)d_in[0];   // [1,8,16,64] fp32
    const float4* cache = (const float4*)d_in[1];   // [1,8,65536,64] fp32
    float4* out = (float4*)d_out;                   // [1,8,65552,64] fp32

    // Bulk cache copy: 8,388,608 float4s; grid-stride with ~2048 blocks.
    kv_copy_cache<<<2048, 256, 0, stream>>>(cache, out);
    // x tail: 2048 float4s.
    kv_copy_x<<<8, 256, 0, stream>>>(x, out);
}

// Round 3
// 44.583 us; speedup vs baseline: 1.0308x; 1.0308x over previous
//
#include <hip/hip_runtime.h>

// KV cache append: out[b,h] = concat(k_cache[b,h] (65536 rows), x[b,h] (16 rows))
// B=1, H=8, S=65536, D=64, NEW=16, fp32.
// Per head: cache = 65536*64 = 4,194,304 floats = 1,048,576 float4 (== 2^20)
//           x     =    16*64 =     1,024 floats =       256 float4
//           out   = 65552*64 = 4,195,328 floats = 1,048,832 float4

typedef float f32x4 __attribute__((ext_vector_type(4)));

#define CACHE_F4_PER_HEAD (1048576LL)   // 2^20
#define OUT_F4_PER_HEAD   (1048832LL)
#define X_F4_TOTAL        (2048LL)      // 8 heads * 256
#define CACHE_F4_TOTAL    (8388608LL)   // 8 * 2^20
#define N_HEADS           (8)

__global__ void kv_append(const f32x4* __restrict__ cache,
                          const f32x4* __restrict__ x,
                          f32x4* __restrict__ dst) {
    const long long total = CACHE_F4_TOTAL + X_F4_TOTAL;
    long long i = (long long)blockIdx.x * blockDim.x + threadIdx.x;
    const long long stride = (long long)gridDim.x * blockDim.x;
    for (; i < total; i += stride) {
        if (i < CACHE_F4_TOTAL) {
            long long head = i >> 20;
            long long r    = i & (CACHE_F4_PER_HEAD - 1);
            f32x4 v = cache[i];
            __builtin_nontemporal_store(v, &dst[head * OUT_F4_PER_HEAD + r]);
        } else {
            long long j    = i - CACHE_F4_TOTAL;     // 0..2047
            long long head = j >> 8;
            long long r    = j & 255;
            f32x4 v = x[j];
            __builtin_nontemporal_store(
                v, &dst[head * OUT_F4_PER_HEAD + CACHE_F4_PER_HEAD + r]);
        }
    }
}

extern "C" void kernel_launch(void* const* d_in, const int* in_sizes, int n_in,
                              void* d_out, int out_size, void* d_ws, size_t ws_size,
                              hipStream_t stream) {
    const f32x4* x     = (const f32x4*)d_in[0];   // [1,8,16,64] fp32
    const f32x4* cache = (const f32x4*)d_in[1];   // [1,8,65536,64] fp32
    f32x4* out = (f32x4*)d_out;                   // [1,8,65552,64] fp32

    // 8,390,656 float4s total; 2048 blocks x 256 threads, 16 iters/thread.
    kv_append<<<2048, 256, 0, stream>>>(cache, x, out);
}